// Round 1
// baseline (374.866 us; speedup 1.0000x reference)
//
#include <hip/hip_runtime.h>
#include <hip/hip_bf16.h>

// GateLayer: y[i,g] = c0[g]*(a*b) + c1[g]*(a+b),
//   a = x[i, idx_l[g]], b = x[i, idx_r[g]],
//   c0 = w0 - w1 - 2*w2, c1 = w1 + w2, w = softmax(alpha[g,:3]).
// B=4096, M=4096, G=16384.

#define B_DIM 4096
#define M_DIM 4096
#define G_DIM 16384

// Packed per-gate record: {il, ir, bits(c0), bits(c1)} = 16 bytes.
__global__ __launch_bounds__(256) void prep_gates(
    const int* __restrict__ idx_l, const int* __restrict__ idx_r,
    const float* __restrict__ alpha, int4* __restrict__ gates, int G)
{
    int g = blockIdx.x * blockDim.x + threadIdx.x;
    if (g >= G) return;
    float a0 = alpha[g * 3 + 0];
    float a1 = alpha[g * 3 + 1];
    float a2 = alpha[g * 3 + 2];
    float m  = fmaxf(a0, fmaxf(a1, a2));
    float e0 = expf(a0 - m);
    float e1 = expf(a1 - m);
    float e2 = expf(a2 - m);
    float inv = 1.0f / (e0 + e1 + e2);
    float w0 = e0 * inv, w1 = e1 * inv, w2 = e2 * inv;
    float c0 = w0 - w1 - 2.0f * w2;   // coefficient on a*b
    float c1 = w1 + w2;               // coefficient on (a+b)
    int4 rec;
    rec.x = idx_l[g];
    rec.y = idx_r[g];
    rec.z = __float_as_int(c0);
    rec.w = __float_as_int(c1);
    gates[g] = rec;
}

// One block per row. Stage the row in LDS (16 KB), gather per gate.
__global__ __launch_bounds__(256) void gate_main(
    const float* __restrict__ x, const int4* __restrict__ gates,
    float* __restrict__ out, int M, int G)
{
    __shared__ float row[M_DIM];

    const int b = blockIdx.x;
    const float* xrow = x + (size_t)b * M;

    // Coalesced float4 staging of the row into LDS: 1024 float4 / 256 thr = 4 each.
    const float4* xr4  = reinterpret_cast<const float4*>(xrow);
    float4*       row4 = reinterpret_cast<float4*>(row);
    #pragma unroll
    for (int i = 0; i < M_DIM / 4 / 256; ++i) {
        row4[threadIdx.x + i * 256] = xr4[threadIdx.x + i * 256];
    }
    __syncthreads();

    float* orow = out + (size_t)b * G;

    // Each thread: 4 consecutive gates per iter, one float4 store (coalesced).
    for (int g4 = threadIdx.x; g4 < G / 4; g4 += 256) {
        const int g = g4 * 4;
        float4 y;
        float* yp = &y.x;
        #pragma unroll
        for (int k = 0; k < 4; ++k) {
            int4 rec = gates[g + k];
            float a  = row[rec.x];
            float bb = row[rec.y];
            float c0 = __int_as_float(rec.z);
            float c1 = __int_as_float(rec.w);
            yp[k] = c0 * (a * bb) + c1 * (a + bb);
        }
        reinterpret_cast<float4*>(orow)[g4] = y;
    }
}

extern "C" void kernel_launch(void* const* d_in, const int* in_sizes, int n_in,
                              void* d_out, int out_size, void* d_ws, size_t ws_size,
                              hipStream_t stream)
{
    const float* x     = (const float*)d_in[0];
    const int*   idx_l = (const int*)d_in[1];
    const int*   idx_r = (const int*)d_in[2];
    const float* alpha = (const float*)d_in[3];
    float*       out   = (float*)d_out;

    int4* gates = (int4*)d_ws;  // G * 16 B = 256 KB scratch

    prep_gates<<<(G_DIM + 255) / 256, 256, 0, stream>>>(idx_l, idx_r, alpha, gates, G_DIM);
    gate_main<<<B_DIM, 256, 0, stream>>>(x, gates, out, M_DIM, G_DIM);
}

// Round 5
// 332.749 us; speedup vs baseline: 1.1266x; 1.1266x over previous
//
#include <hip/hip_runtime.h>
#include <hip/hip_bf16.h>

// GateLayer: y[i,g] = c0[g]*(a*b) + c1[g]*(a+b),
//   a = x[i, idx_l[g]], b = x[i, idx_r[g]],
//   c0 = w0 - w1 - 2*w2, c1 = w1 + w2, w = softmax(alpha[g,:3]).
// B=4096, M=4096, G=16384.

#define B_DIM 4096
#define M_DIM 4096
#define G_DIM 16384
#define ROWS  2     // rows per block (LDS = ROWS*16 KB)

// Packed per-gate record: {il, ir, bits(c0), bits(c1)} = 16 bytes.
__global__ __launch_bounds__(256) void prep_gates(
    const int* __restrict__ idx_l, const int* __restrict__ idx_r,
    const float* __restrict__ alpha, int4* __restrict__ gates, int G)
{
    int g = blockIdx.x * blockDim.x + threadIdx.x;
    if (g >= G) return;
    float a0 = alpha[g * 3 + 0];
    float a1 = alpha[g * 3 + 1];
    float a2 = alpha[g * 3 + 2];
    float m  = fmaxf(a0, fmaxf(a1, a2));
    float e0 = expf(a0 - m);
    float e1 = expf(a1 - m);
    float e2 = expf(a2 - m);
    float inv = 1.0f / (e0 + e1 + e2);
    float w0 = e0 * inv, w1 = e1 * inv, w2 = e2 * inv;
    float c0 = w0 - w1 - 2.0f * w2;   // coefficient on a*b
    float c1 = w1 + w2;               // coefficient on (a+b)
    int4 rec;
    rec.x = idx_l[g];
    rec.y = idx_r[g];
    rec.z = __float_as_int(c0);
    rec.w = __float_as_int(c1);
    gates[g] = rec;
}

// ROWS rows per block. Stage rows in LDS; one gate per lane per iteration:
// gate-record loads are fully coalesced (64 lanes x 16 B = 1 KB contiguous),
// each record amortized over ROWS outputs.
__global__ __launch_bounds__(256) void gate_main(
    const float* __restrict__ x, const int4* __restrict__ gates,
    float* __restrict__ out)
{
    __shared__ float rows[ROWS * M_DIM];

    const int b0 = blockIdx.x * ROWS;
    const float* xbase = x + (size_t)b0 * M_DIM;

    // Coalesced float4 staging: ROWS*1024 float4 / 256 thr = ROWS*4 each.
    const float4* xr4   = reinterpret_cast<const float4*>(xbase);
    float4*       rows4 = reinterpret_cast<float4*>(rows);
    #pragma unroll
    for (int i = 0; i < ROWS * M_DIM / 4 / 256; ++i) {
        rows4[threadIdx.x + i * 256] = xr4[threadIdx.x + i * 256];
    }
    __syncthreads();

    float* o0 = out + (size_t)b0 * G_DIM;

    #pragma unroll 4
    for (int g = threadIdx.x; g < G_DIM; g += 256) {
        int4 rec = gates[g];            // coalesced: lane stride 16 B
        float c0 = __int_as_float(rec.z);
        float c1 = __int_as_float(rec.w);
        #pragma unroll
        for (int r = 0; r < ROWS; ++r) {
            float a  = rows[r * M_DIM + rec.x];
            float bb = rows[r * M_DIM + rec.y];
            o0[(size_t)r * G_DIM + g] = c0 * (a * bb) + c1 * (a + bb);
        }
    }
}

extern "C" void kernel_launch(void* const* d_in, const int* in_sizes, int n_in,
                              void* d_out, int out_size, void* d_ws, size_t ws_size,
                              hipStream_t stream)
{
    const float* x     = (const float*)d_in[0];
    const int*   idx_l = (const int*)d_in[1];
    const int*   idx_r = (const int*)d_in[2];
    const float* alpha = (const float*)d_in[3];
    float*       out   = (float*)d_out;

    int4* gates = (int4*)d_ws;  // G * 16 B = 256 KB scratch

    prep_gates<<<(G_DIM + 255) / 256, 256, 0, stream>>>(idx_l, idx_r, alpha, gates, G_DIM);
    gate_main<<<B_DIM / ROWS, 256, 0, stream>>>(x, gates, out);
}